// Round 3
// baseline (70.138 us; speedup 1.0000x reference)
//
#include <hip/hip_runtime.h>
#include <math.h>

#define TOKEN_NUMS 2004
#define PAD_IDX    2003
#define B_DIM      32
#define S_DIM      512
#define SP_DIM     510              // S - 2
#define NROWS      (B_DIM * SP_DIM) // 16320
#define NCHUNKS    (NROWS / 64)     // 255 chunks of 64 tokens
#define ROW_F4     (TOKEN_NUMS / 4) // 501 float4s per row
#define WPB        16               // waves per block
#define GRID_N     (NROWS / WPB)    // 1020 blocks

// Fused: per-row argmax (all blocks) + last-block loss phase.
__global__ __launch_bounds__(1024) void cvl_fused_kernel(
    const float* __restrict__ pred,
    const float* __restrict__ gt_acc,
    const float* __restrict__ gt_steer,
    const int*   __restrict__ gt_rev,
    float*       __restrict__ out,
    int*         __restrict__ tok,
    unsigned int* __restrict__ counter)
{
    __shared__ int   s_cnt[NCHUNKS];
    __shared__ int   s_base[NCHUNKS + 1];
    __shared__ float s_red[3][WPB];
    __shared__ int   s_last;

    int tid  = (int)threadIdx.x;
    int wv   = tid >> 6;
    int lane = tid & 63;

    // ---------------- Phase 1: argmax of one row per wave ----------------
    int wid = (int)blockIdx.x * WPB + wv;        // row id, 0..16319
    int b = wid / SP_DIM;
    int s = wid - b * SP_DIM;
    const float4* row = reinterpret_cast<const float4*>(
        pred + (size_t)(b * S_DIM + s) * TOKEN_NUMS);

    // 501 = 7*64 + 53: 7 unconditional strided loads + 1 predicated tail
    float4 v[8];
    #pragma unroll
    for (int k = 0; k < 7; ++k) v[k] = row[lane + 64 * k];
    v[7] = (lane < (ROW_F4 - 7 * 64))
         ? row[lane + 7 * 64]
         : make_float4(-INFINITY, -INFINITY, -INFINITY, -INFINITY);

    float best = -INFINITY;
    int   bidx = 0x7fffffff;
    #pragma unroll
    for (int k = 0; k < 8; ++k) {
        int base = (lane + 64 * k) << 2;
        if (v[k].x > best) { best = v[k].x; bidx = base;     }
        if (v[k].y > best) { best = v[k].y; bidx = base + 1; }
        if (v[k].z > best) { best = v[k].z; bidx = base + 2; }
        if (v[k].w > best) { best = v[k].w; bidx = base + 3; }
    }
    #pragma unroll
    for (int off = 32; off >= 1; off >>= 1) {
        float ov = __shfl_xor(best, off);
        int   oi = __shfl_xor(bidx, off);
        if (ov > best || (ov == best && oi < bidx)) { best = ov; bidx = oi; }
    }
    if (lane == 0) tok[wid] = bidx;

    // ---------------- Ticket: last block proceeds to loss phase ----------------
    __syncthreads();   // drains all vmem (tok stores) block-wide before ticket
    if (tid == 0) {
        // acq_rel + agent scope: release publishes tok stores device-wide
        // (cross-XCD), acquire invalidates caches for the re-read below.
        unsigned int t = __hip_atomic_fetch_add(counter, 1u,
                            __ATOMIC_ACQ_REL, __HIP_MEMORY_SCOPE_AGENT);
        s_last = (t == GRID_N - 1) ? 1 : 0;
    }
    __syncthreads();
    if (!s_last) return;

    // ---------------- Phase 2 (last block only): scan + losses ----------------
    // Single pass over tok: 16 chunks per wave, cached in registers.
    int tk[16];
    #pragma unroll
    for (int k = 0; k < 16; ++k) {
        int c = wv * 16 + k;
        tk[k] = (c < NCHUNKS) ? tok[c * 64 + lane] : PAD_IDX;
    }
    #pragma unroll
    for (int k = 0; k < 16; ++k) {
        int c = wv * 16 + k;
        if (c < NCHUNKS) {
            unsigned long long m = __ballot(tk[k] != PAD_IDX);
            if (lane == 0) s_cnt[c] = __popcll(m);
        }
    }
    __syncthreads();

    if (tid == 0) {   // order-exact serial exclusive scan (255 adds)
        int run = 0;
        for (int c = 0; c < NCHUNKS; ++c) { s_base[c] = run; run += s_cnt[c]; }
        s_base[NCHUNKS] = run;
    }
    __syncthreads();

    float cnt = fmaxf((float)s_base[NCHUNKS], 1.0f);
    const float lse   = log1pf(expf(1.0f));
    const float scale = 1.0f / 9.0f;   // 1/(BASE-1)

    float accAS = 0.0f, accR = 0.0f, ceC = 0.0f;

    #pragma unroll
    for (int k = 0; k < 16; ++k) {
        int c = wv * 16 + k;
        if (c >= NCHUNKS) continue;
        bool valid = (tk[k] != PAD_IDX);
        unsigned long long m = __ballot(valid);
        if (valid) {
            int pos = s_base[c] + __popcll(m & ((1ull << lane) - 1ull));
            int t2  = tk[k];

            int rev = t2 & 1;
            int st  = (t2 >> 1) % 10;
            int bt  = (t2 / 20) % 10;
            int tt  = (t2 / 200) % 10;

            float acc_p   = (float)tt * scale - (float)bt * scale;
            float steer_p = (float)st * scale * 2.0f - 1.0f;

            float d = acc_p - gt_acc[pos];
            float a = fabsf(d);
            accAS += (a < 1.0f) ? 0.5f * d * d : a - 0.5f;

            d = steer_p - gt_steer[pos];
            a = fabsf(d);
            accAS += (a < 1.0f) ? 0.5f * d * d : a - 0.5f;

            int g = gt_rev[pos];
            if (g != PAD_IDX) {
                accR += lse - ((rev == g) ? 1.0f : 0.0f);
                ceC  += 1.0f;
            }
        }
    }

    #pragma unroll
    for (int o = 32; o >= 1; o >>= 1) {
        accAS += __shfl_down(accAS, o);
        accR  += __shfl_down(accR,  o);
        ceC   += __shfl_down(ceC,   o);
    }
    if (lane == 0) { s_red[0][wv] = accAS; s_red[1][wv] = accR; s_red[2][wv] = ceC; }
    __syncthreads();

    if (tid == 0) {
        float rAS = 0.0f, rR = 0.0f, rC = 0.0f;
        #pragma unroll
        for (int w = 0; w < WPB; ++w) {
            rAS += s_red[0][w]; rR += s_red[1][w]; rC += s_red[2][w];
        }
        out[0] = rAS / cnt;
        out[1] = rR / fmaxf(rC, 1.0f);
    }
}

extern "C" void kernel_launch(void* const* d_in, const int* in_sizes, int n_in,
                              void* d_out, int out_size, void* d_ws, size_t ws_size,
                              hipStream_t stream)
{
    const float* pred     = (const float*)d_in[0];
    const float* gt_acc   = (const float*)d_in[1];
    const float* gt_steer = (const float*)d_in[2];
    const int*   gt_rev   = (const int*)d_in[3];
    float*       out      = (float*)d_out;
    int*          tok     = (int*)d_ws;                       // 65280 B
    unsigned int* counter = (unsigned int*)((char*)d_ws + NROWS * sizeof(int));

    hipMemsetAsync(counter, 0, sizeof(unsigned int), stream); // graph-safe
    hipLaunchKernelGGL(cvl_fused_kernel, dim3(GRID_N), dim3(1024), 0, stream,
                       pred, gt_acc, gt_steer, gt_rev, out, tok, counter);
}

// Round 4
// 35.103 us; speedup vs baseline: 1.9981x; 1.9981x over previous
//
#include <hip/hip_runtime.h>
#include <math.h>

#define TOKEN_NUMS 2004
#define PAD_IDX    2003
#define B_DIM      32
#define S_DIM      512
#define SP_DIM     510              // S - 2
#define NROWS      (B_DIM * SP_DIM) // 16320
#define NCHUNKS    (NROWS / 64)     // 255 chunks of 64 tokens
#define ROW_F4     (TOKEN_NUMS / 4) // 501 float4s per row

// ---------------- Kernel 1: per-row argmax (identical to R2 — proven) ----------------
__global__ __launch_bounds__(256) void cvl_argmax_kernel(
    const float* __restrict__ pred, int* __restrict__ tok)
{
    int wid  = (int)((blockIdx.x * blockDim.x + threadIdx.x) >> 6);
    int lane = (int)(threadIdx.x & 63);
    if (wid >= NROWS) return;

    int b = wid / SP_DIM;
    int s = wid - b * SP_DIM;
    const float4* row = reinterpret_cast<const float4*>(
        pred + (size_t)(b * S_DIM + s) * TOKEN_NUMS);

    float4 v[8];
    #pragma unroll
    for (int k = 0; k < 7; ++k) v[k] = row[lane + 64 * k];
    v[7] = (lane < (ROW_F4 - 7 * 64))
         ? row[lane + 7 * 64]
         : make_float4(-INFINITY, -INFINITY, -INFINITY, -INFINITY);

    float best = -INFINITY;
    int   bidx = 0x7fffffff;
    #pragma unroll
    for (int k = 0; k < 8; ++k) {
        int base = (lane + 64 * k) << 2;
        if (v[k].x > best) { best = v[k].x; bidx = base;     }
        if (v[k].y > best) { best = v[k].y; bidx = base + 1; }
        if (v[k].z > best) { best = v[k].z; bidx = base + 2; }
        if (v[k].w > best) { best = v[k].w; bidx = base + 3; }
    }
    #pragma unroll
    for (int off = 32; off >= 1; off >>= 1) {
        float ov = __shfl_xor(best, off);
        int   oi = __shfl_xor(bidx, off);
        if (ov > best || (ov == best && oi < bidx)) { best = ov; bidx = oi; }
    }
    if (lane == 0) tok[wid] = bidx;
}

// ---------------- Kernel 2 (rebuilt): reg-resident toks, parallel int scan, MLP gathers ----
// Single block, 1024 threads = 16 waves, 16 chunks per wave.
__global__ __launch_bounds__(1024) void cvl_loss_kernel(
    const int*   __restrict__ tok,
    const float* __restrict__ gt_acc,
    const float* __restrict__ gt_steer,
    const int*   __restrict__ gt_rev,
    float*       __restrict__ out)
{
    __shared__ int   s_cnt[256];       // [255] real + 1 pad
    __shared__ int   s_base[256];      // exclusive bases; s_base[255] = total
    __shared__ float s_red[3][16];

    int tid  = (int)threadIdx.x;
    int wv   = tid >> 6;          // 0..15
    int lane = tid & 63;

    if (tid == 0) s_cnt[255] = 0;

    // Phase A: all 16 chunk-toks into registers (independent loads), ballot counts
    int tk[16];
    #pragma unroll
    for (int k = 0; k < 16; ++k) {
        int c = wv * 16 + k;
        tk[k] = (c < NCHUNKS) ? tok[c * 64 + lane] : PAD_IDX;
    }
    #pragma unroll
    for (int k = 0; k < 16; ++k) {
        int c = wv * 16 + k;
        if (c < NCHUNKS) {
            unsigned long long m = __ballot(tk[k] != PAD_IDX);
            if (lane == 0) s_cnt[c] = __popcll(m);
        }
    }
    __syncthreads();

    // Phase B: wave 0 does an exact parallel int scan (4 counts per lane)
    if (wv == 0) {
        int c0 = lane << 2;
        int a0 = s_cnt[c0], a1 = s_cnt[c0 + 1], a2 = s_cnt[c0 + 2], a3 = s_cnt[c0 + 3];
        int ls = a0 + a1 + a2 + a3;
        int incl = ls;
        #pragma unroll
        for (int off = 1; off <= 32; off <<= 1) {
            int u = __shfl_up(incl, off);
            if (lane >= off) incl += u;
        }
        int base = incl - ls;
        s_base[c0]     = base;
        s_base[c0 + 1] = base + a0;
        s_base[c0 + 2] = base + a0 + a1;
        s_base[c0 + 3] = base + a0 + a1 + a2;   // lane 63: s_base[255] = total (a3 pad = 0)
    }
    __syncthreads();

    int   total = s_base[255];
    float cnt   = fmaxf((float)total, 1.0f);
    const float lse   = log1pf(expf(1.0f));
    const float scale = 1.0f / 9.0f;   // 1/(BASE-1)

    // Phase C: all positions first (no loads), then unrolled gather+accumulate
    int pos[16];
    #pragma unroll
    for (int k = 0; k < 16; ++k) {
        int c = wv * 16 + k;
        if (c < NCHUNKS) {
            unsigned long long m = __ballot(tk[k] != PAD_IDX);
            int p = s_base[c] + __popcll(m & ((1ull << lane) - 1ull));
            pos[k] = (p < NROWS) ? p : 0;   // invalid lanes: harmless in-bounds addr
        } else {
            pos[k] = 0;
        }
    }

    float accAS = 0.0f, accR = 0.0f, ceC = 0.0f;
    #pragma unroll
    for (int k = 0; k < 16; ++k) {
        int c = wv * 16 + k;
        bool valid = (c < NCHUNKS) && (tk[k] != PAD_IDX);
        float ga = gt_acc[pos[k]];
        float gs = gt_steer[pos[k]];
        int   gr = gt_rev[pos[k]];
        if (valid) {
            int t2  = tk[k];
            int rev = t2 & 1;
            int st  = (t2 >> 1) % 10;
            int bt  = (t2 / 20) % 10;
            int tt  = (t2 / 200) % 10;

            float acc_p   = (float)tt * scale - (float)bt * scale;
            float steer_p = (float)st * scale * 2.0f - 1.0f;

            float d = acc_p - ga;
            float a = fabsf(d);
            accAS += (a < 1.0f) ? 0.5f * d * d : a - 0.5f;

            d = steer_p - gs;
            a = fabsf(d);
            accAS += (a < 1.0f) ? 0.5f * d * d : a - 0.5f;

            if (gr != PAD_IDX) {
                accR += lse - ((rev == gr) ? 1.0f : 0.0f);
                ceC  += 1.0f;
            }
        }
    }

    #pragma unroll
    for (int o = 32; o >= 1; o >>= 1) {
        accAS += __shfl_down(accAS, o);
        accR  += __shfl_down(accR,  o);
        ceC   += __shfl_down(ceC,   o);
    }
    if (lane == 0) { s_red[0][wv] = accAS; s_red[1][wv] = accR; s_red[2][wv] = ceC; }
    __syncthreads();

    if (tid == 0) {
        float rAS = 0.0f, rR = 0.0f, rC = 0.0f;
        #pragma unroll
        for (int w = 0; w < 16; ++w) {
            rAS += s_red[0][w]; rR += s_red[1][w]; rC += s_red[2][w];
        }
        out[0] = rAS / cnt;
        out[1] = rR / fmaxf(rC, 1.0f);
    }
}

extern "C" void kernel_launch(void* const* d_in, const int* in_sizes, int n_in,
                              void* d_out, int out_size, void* d_ws, size_t ws_size,
                              hipStream_t stream)
{
    const float* pred     = (const float*)d_in[0];
    const float* gt_acc   = (const float*)d_in[1];
    const float* gt_steer = (const float*)d_in[2];
    const int*   gt_rev   = (const int*)d_in[3];
    float*       out      = (float*)d_out;
    int*         tok      = (int*)d_ws;   // NROWS ints = 65280 B

    int blocks = (NROWS + 3) / 4;         // 4 waves/block, one wave per row
    hipLaunchKernelGGL(cvl_argmax_kernel, dim3(blocks), dim3(256), 0, stream, pred, tok);
    hipLaunchKernelGGL(cvl_loss_kernel, dim3(1), dim3(1024), 0, stream,
                       tok, gt_acc, gt_steer, gt_rev, out);
}